// Round 1
// baseline (1501.909 us; speedup 1.0000x reference)
//
#include <hip/hip_runtime.h>
#include <hip/hip_bf16.h>

#define M_DIM 8192
#define N_DIM 16384
#define K_DIM 4096

typedef short short8 __attribute__((ext_vector_type(8)));
typedef float floatx4 __attribute__((ext_vector_type(4)));

// round-to-nearest-even fp32 -> bf16 bits (inputs are finite normals)
__device__ __forceinline__ unsigned short f2bf(float f) {
    union { float f; unsigned u; } a;
    a.f = f;
    unsigned r = a.u + 0x7FFFu + ((a.u >> 16) & 1u);
    return (unsigned short)(r >> 16);
}

// async global->LDS, 16 bytes per lane
#define GLDS16(g, l)                                                     \
    __builtin_amdgcn_global_load_lds(                                    \
        (const __attribute__((address_space(1))) void*)(g),              \
        (__attribute__((address_space(3))) void*)(l), 16, 0, 0)

// ---------------- conversion kernels (memory-bound) ----------------
__global__ void cvt_x_kernel(const float4* __restrict__ x,
                             ushort4* __restrict__ out, int n4) {
    int idx = blockIdx.x * blockDim.x + threadIdx.x;
    int stride = gridDim.x * blockDim.x;
    for (int i = idx; i < n4; i += stride) {
        float4 v = x[i];
        ushort4 u;
        u.x = f2bf(v.x); u.y = f2bf(v.y); u.z = f2bf(v.z); u.w = f2bf(v.w);
        out[i] = u;
    }
}

__global__ void cvt_w_kernel(const int4* __restrict__ w,
                             ushort4* __restrict__ out,
                             const int* __restrict__ zp_p, int n4) {
    int zp = *zp_p;
    int idx = blockIdx.x * blockDim.x + threadIdx.x;
    int stride = gridDim.x * blockDim.x;
    for (int i = idx; i < n4; i += stride) {
        int4 q = w[i];
        ushort4 u;
        u.x = f2bf((float)(q.x - zp));
        u.y = f2bf((float)(q.y - zp));
        u.z = f2bf((float)(q.z - zp));
        u.w = f2bf((float)(q.w - zp));
        out[i] = u;
    }
}

// ---------------- bf16 MFMA GEMM, 128x128 tile, BK=32, 4 waves ----------------
// A: [M,K] bf16 row-major (x). B: [N,K] bf16 row-major (w, i.e. B^T input).
// out[m,n] = (sum_k A[m,k]*B[n,k]) * scale + bias[n]
template <int PRECONV>
__global__ __launch_bounds__(256)
void gemm_kernel(const ushort* __restrict__ A, const ushort* __restrict__ B,
                 const float* __restrict__ Xf, const int* __restrict__ Wq,
                 const float* __restrict__ bias,
                 const float* __restrict__ scale_p,
                 const int* __restrict__ zp_p,
                 float* __restrict__ out) {
    const int NB = N_DIM / 128;  // 128 block-cols
    int nwg = gridDim.x;         // 8192, divisible by 8
    int cpx = nwg >> 3;
    int bid = blockIdx.x;
    int swz = (bid & 7) * cpx + (bid >> 3);  // XCD-contiguous chunks
    int bx = swz % NB;
    int by = swz / NB;
    const int brow = by * 128;
    const int bcol = bx * 128;

    __shared__ __align__(16) ushort sA[128 * 32];
    __shared__ __align__(16) ushort sB[128 * 32];

    const int t = threadIdx.x;
    const int lane = t & 63;
    const int wid = t >> 6;
    const int wr = wid >> 1;  // wave row 0..1
    const int wc = wid & 1;   // wave col 0..1

    floatx4 acc[4][4] = {};

    // staging source addresses (PRECONV path): 16B (8 bf16) per lane per issue
    const int ar = t >> 2;           // row 0..63
    const int ac = (t & 3) << 3;     // col {0,8,16,24}
    const ushort* gA0 = A + (size_t)(brow + ar) * K_DIM + ac;
    const ushort* gA1 = gA0 + (size_t)64 * K_DIM;
    const ushort* gB0 = B + (size_t)(bcol + ar) * K_DIM + ac;
    const ushort* gB1 = gB0 + (size_t)64 * K_DIM;

    // fallback staging coords: 16 elems per thread
    const int xr = t >> 1;           // row 0..127
    const int xc = (t & 1) << 4;     // col {0,16}
    int zp = 0;
    if (!PRECONV) zp = *zp_p;

    const int arow = wr * 64 + (lane & 15);
    const int acol = (lane >> 4) << 3;
    const int brow_f = wc * 64 + (lane & 15);

    for (int k0 = 0; k0 < K_DIM; k0 += 32) {
        __syncthreads();
        if (PRECONV) {
            GLDS16(gA0 + k0, &sA[t * 8]);
            GLDS16(gA1 + k0, &sA[2048 + t * 8]);
            GLDS16(gB0 + k0, &sB[t * 8]);
            GLDS16(gB1 + k0, &sB[2048 + t * 8]);
        } else {
            const float* gx = Xf + (size_t)(brow + xr) * K_DIM + k0 + xc;
            ushort* dA = &sA[xr * 32 + xc];
            #pragma unroll
            for (int i = 0; i < 4; ++i) {
                float4 v = ((const float4*)gx)[i];
                ushort4 u;
                u.x = f2bf(v.x); u.y = f2bf(v.y); u.z = f2bf(v.z); u.w = f2bf(v.w);
                *(ushort4*)(dA + i * 4) = u;
            }
            const int* gw = Wq + (size_t)(bcol + xr) * K_DIM + k0 + xc;
            ushort* dB = &sB[xr * 32 + xc];
            #pragma unroll
            for (int i = 0; i < 4; ++i) {
                int4 q = ((const int4*)gw)[i];
                ushort4 u;
                u.x = f2bf((float)(q.x - zp));
                u.y = f2bf((float)(q.y - zp));
                u.z = f2bf((float)(q.z - zp));
                u.w = f2bf((float)(q.w - zp));
                *(ushort4*)(dB + i * 4) = u;
            }
        }
        __syncthreads();

        short8 af[4], bfr[4];
        #pragma unroll
        for (int m = 0; m < 4; ++m)
            af[m] = *(const short8*)&sA[(arow + m * 16) * 32 + acol];
        #pragma unroll
        for (int n = 0; n < 4; ++n)
            bfr[n] = *(const short8*)&sB[(brow_f + n * 16) * 32 + acol];

        #pragma unroll
        for (int m = 0; m < 4; ++m)
            #pragma unroll
            for (int n = 0; n < 4; ++n)
                acc[m][n] = __builtin_amdgcn_mfma_f32_16x16x32_bf16(
                    af[m], bfr[n], acc[m][n], 0, 0, 0);
    }

    // epilogue: out = acc*scale + bias
    const float scale = *scale_p;
    const int colbase = bcol + wc * 64 + (lane & 15);
    const int rowbase = brow + wr * 64 + ((lane >> 4) << 2);
    float bv[4];
    #pragma unroll
    for (int n = 0; n < 4; ++n) bv[n] = bias[colbase + n * 16];
    #pragma unroll
    for (int m = 0; m < 4; ++m) {
        const int r0 = rowbase + m * 16;
        #pragma unroll
        for (int j = 0; j < 4; ++j) {
            float* orow = out + (size_t)(r0 + j) * N_DIM;
            #pragma unroll
            for (int n = 0; n < 4; ++n)
                orow[colbase + n * 16] = acc[m][n][j] * scale + bv[n];
        }
    }
}

extern "C" void kernel_launch(void* const* d_in, const int* in_sizes, int n_in,
                              void* d_out, int out_size, void* d_ws, size_t ws_size,
                              hipStream_t stream) {
    const float* x = (const float*)d_in[0];       // [8192,4096] fp32
    const int* wq = (const int*)d_in[1];          // [16384,4096] int32
    const float* bias = (const float*)d_in[2];    // [16384] fp32
    const float* scale = (const float*)d_in[3];   // scalar fp32
    const int* zp = (const int*)d_in[4];          // scalar int32
    float* out = (float*)d_out;

    const size_t xb_bytes = (size_t)M_DIM * K_DIM * 2;  // 64 MiB
    const size_t wb_bytes = (size_t)N_DIM * K_DIM * 2;  // 128 MiB
    const int nblocks = (M_DIM / 128) * (N_DIM / 128);  // 8192

    if (ws_size >= xb_bytes + wb_bytes) {
        ushort* xb = (ushort*)d_ws;
        ushort* wb = (ushort*)((char*)d_ws + xb_bytes);
        cvt_x_kernel<<<2048, 256, 0, stream>>>((const float4*)x, (ushort4*)xb,
                                               (M_DIM * K_DIM) / 4);
        cvt_w_kernel<<<2048, 256, 0, stream>>>((const int4*)wq, (ushort4*)wb, zp,
                                               (N_DIM * K_DIM) / 4);
        gemm_kernel<1><<<nblocks, 256, 0, stream>>>(xb, wb, nullptr, nullptr,
                                                    bias, scale, zp, out);
    } else {
        gemm_kernel<0><<<nblocks, 256, 0, stream>>>(nullptr, nullptr, x, wq,
                                                    bias, scale, zp, out);
    }
}

// Round 2
// 1060.992 us; speedup vs baseline: 1.4156x; 1.4156x over previous
//
#include <hip/hip_runtime.h>
#include <hip/hip_bf16.h>

#define M_DIM 8192
#define N_DIM 16384
#define K_DIM 4096

typedef short short8 __attribute__((ext_vector_type(8)));
typedef float floatx4 __attribute__((ext_vector_type(4)));

__device__ __forceinline__ unsigned short f2bf(float f) {
    union { float f; unsigned u; } a;
    a.f = f;
    unsigned r = a.u + 0x7FFFu + ((a.u >> 16) & 1u);
    return (unsigned short)(r >> 16);
}

#define GLDS16(g, l)                                                     \
    __builtin_amdgcn_global_load_lds(                                    \
        (const __attribute__((address_space(1))) void*)(g),              \
        (__attribute__((address_space(3))) void*)(l), 16, 0, 0)

#define SBAR() asm volatile("s_barrier" ::: "memory")
#define WAIT_LGKM0() asm volatile("s_waitcnt lgkmcnt(0)" ::: "memory")
#define WAIT_VM6() asm volatile("s_waitcnt vmcnt(6)" ::: "memory")
#define WAIT_VM0() asm volatile("s_waitcnt vmcnt(0)" ::: "memory")

// ---------------- conversion kernels (memory-bound) ----------------
__global__ void cvt_x_kernel(const float4* __restrict__ x,
                             ushort4* __restrict__ out, int n4) {
    int idx = blockIdx.x * blockDim.x + threadIdx.x;
    int stride = gridDim.x * blockDim.x;
    for (int i = idx; i < n4; i += stride) {
        float4 v = x[i];
        ushort4 u;
        u.x = f2bf(v.x); u.y = f2bf(v.y); u.z = f2bf(v.z); u.w = f2bf(v.w);
        out[i] = u;
    }
}

__global__ void cvt_w_kernel(const int4* __restrict__ w,
                             ushort4* __restrict__ out,
                             const int* __restrict__ zp_p, int n4) {
    int zp = *zp_p;
    int idx = blockIdx.x * blockDim.x + threadIdx.x;
    int stride = gridDim.x * blockDim.x;
    for (int i = idx; i < n4; i += stride) {
        int4 q = w[i];
        ushort4 u;
        u.x = f2bf((float)(q.x - zp));
        u.y = f2bf((float)(q.y - zp));
        u.z = f2bf((float)(q.z - zp));
        u.w = f2bf((float)(q.w - zp));
        out[i] = u;
    }
}

// ================= 256x256 8-phase bf16 GEMM =================
// A: [M,K] bf16 (x). B: [N,K] bf16 (dequant w). out[m,n] = (sum A*B)*scale + bias[n]
// 8 waves (2 M x 4 N), BK=64, LDS 128KB = 2buf x (A 32KB + B 32KB).
// Per buffer: A = [mh(2)][wm(2)][row64][128B], B = [nh(2)][wn(4)][row32][128B].
// Swizzle (involution): byte ^= ((byte>>7)&7)<<4  (row low bits -> 16B slot).
// global_load_lds dest is linear; source global addr is pre-inverse-swizzled.

#define LOAD_A(BUF, MH)                                                    \
    do {                                                                   \
        const char* p_ = smem + (BUF)*65536 + (MH)*16384 + wm*8192;        \
        _Pragma("unroll") for (int mf = 0; mf < 4; ++mf) {                 \
            aF[mf][0] = *(const short8*)(p_ + mf*2048 + laneK0);           \
            aF[mf][1] = *(const short8*)(p_ + mf*2048 + laneK1);           \
        }                                                                  \
    } while (0)

#define LOAD_B(BUF, NH)                                                    \
    do {                                                                   \
        const char* p_ = smem + (BUF)*65536 + 32768 + (NH)*16384 + wn*4096;\
        _Pragma("unroll") for (int nf = 0; nf < 2; ++nf) {                 \
            bF[nf][0] = *(const short8*)(p_ + nf*2048 + laneK0);           \
            bF[nf][1] = *(const short8*)(p_ + nf*2048 + laneK1);           \
        }                                                                  \
    } while (0)

#define STAGE_A(BUF, MH, KT)                                               \
    do {                                                                   \
        GLDS16(Aq + aoff0 + (MH)*262144 + (size_t)(KT)*64,                 \
               smem + (BUF)*65536 + (MH)*16384 + st16);                    \
        GLDS16(Aq + aoff1 + (MH)*262144 + (size_t)(KT)*64,                 \
               smem + (BUF)*65536 + (MH)*16384 + 8192 + st16);             \
    } while (0)

#define STAGE_B(BUF, NH, KT)                                               \
    do {                                                                   \
        GLDS16(Bq + boff0 + (NH)*131072 + (size_t)(KT)*64,                 \
               smem + (BUF)*65536 + 32768 + (NH)*16384 + st16);            \
        GLDS16(Bq + boff1 + (NH)*131072 + (size_t)(KT)*64,                 \
               smem + (BUF)*65536 + 32768 + (NH)*16384 + 8192 + st16);     \
    } while (0)

#define MFMA_Q(MH, NH)                                                     \
    do {                                                                   \
        __builtin_amdgcn_s_setprio(1);                                     \
        _Pragma("unroll") for (int mf = 0; mf < 4; ++mf)                   \
        _Pragma("unroll") for (int nf = 0; nf < 2; ++nf)                   \
        _Pragma("unroll") for (int kk = 0; kk < 2; ++kk)                   \
            acc[(MH)*4+mf][(NH)*2+nf] =                                    \
                __builtin_amdgcn_mfma_f32_16x16x32_bf16(                   \
                    aF[mf][kk], bF[nf][kk], acc[(MH)*4+mf][(NH)*2+nf],     \
                    0, 0, 0);                                              \
        __builtin_amdgcn_s_setprio(0);                                     \
    } while (0)

__global__ __launch_bounds__(512, 2)
void gemm8_kernel(const ushort* __restrict__ Aq, const ushort* __restrict__ Bq,
                  const float* __restrict__ bias,
                  const float* __restrict__ scale_p,
                  float* __restrict__ out) {
    __shared__ __align__(16) char smem[131072];

    const int t = threadIdx.x;
    const int lane = t & 63;
    const int wid = t >> 6;
    const int wm = wid >> 2;  // 0..1
    const int wn = wid & 3;   // 0..3

    // XCD-aware bijective swizzle (nwg=2048 divisible by 8)
    int bid = blockIdx.x;
    int sz = (bid & 7) * 256 + (bid >> 3);
    const int bx = sz & 63;   // 64 block-cols
    const int by = sz >> 6;   // 32 block-rows
    const int brow = by << 8;
    const int bcol = bx << 8;

    // swizzled ds_read lane offsets (row = lane&15, slot = lane>>4, kk in {0,1})
    const int laneK0 = (lane & 15) * 128 + (((lane >> 4) * 16) ^ ((lane & 7) << 4));
    const int laneK1 = (lane & 15) * 128 + ((((lane >> 4) * 16) + 64) ^ ((lane & 7) << 4));

    // staging: linear LDS dest (unit-rel byte u = g*8192 + t*16); invert swizzle on source
    size_t aoffs[2], boffs[2];
#pragma unroll
    for (int g = 0; g < 2; ++g) {
        unsigned u = g * 8192 + t * 16;
        unsigned up = u ^ (((u >> 7) & 7) << 4);
        aoffs[g] = (size_t)(brow + ((up >> 13) & 1) * 128 + ((up >> 7) & 63)) * K_DIM
                   + ((up & 127) >> 1);
        boffs[g] = (size_t)(bcol + ((up >> 12) & 3) * 64 + ((up >> 7) & 31)) * K_DIM
                   + ((up & 127) >> 1);
    }
    const size_t aoff0 = aoffs[0], aoff1 = aoffs[1];
    const size_t boff0 = boffs[0], boff1 = boffs[1];
    const int st16 = t * 16;

    floatx4 acc[8][4] = {};
    short8 aF[4][2], bF[2][2];

    const int NT = K_DIM / 64;  // 64

    // ---- prologue: tile0 complete + 3 units of tile1 (SB0(1) comes at kt=0 ph1)
    STAGE_A(0, 0, 0);
    STAGE_B(0, 0, 0);
    STAGE_B(0, 1, 0);
    STAGE_A(0, 1, 0);
    STAGE_A(1, 0, 1);
    STAGE_B(1, 1, 1);
    STAGE_A(1, 1, 1);
    WAIT_VM6();
    SBAR();

    for (int kt = 0; kt < NT; ++kt) {
        const int b = kt & 1;
        const int nb = b ^ 1;

        // ---- phase 1: quadrant (mh=0, nh=0); stage SB0(kt+1)
        LOAD_A(b, 0);
        LOAD_B(b, 0);
        if (kt + 1 < NT) STAGE_B(nb, 0, kt + 1);
        SBAR();
        WAIT_LGKM0();
        MFMA_Q(0, 0);
        SBAR();

        // ---- phase 2: quadrant (0,1); stage SA0(kt+2)
        LOAD_B(b, 1);
        if (kt + 2 < NT) STAGE_A(b, 0, kt + 2);
        SBAR();
        WAIT_LGKM0();
        MFMA_Q(0, 1);
        SBAR();

        // ---- phase 3: quadrant (1,1); stage SB1(kt+2)
        LOAD_A(b, 1);
        if (kt + 2 < NT) STAGE_B(b, 1, kt + 2);
        SBAR();
        WAIT_LGKM0();
        MFMA_Q(1, 1);
        SBAR();

        // ---- phase 4: quadrant (1,0); stage SA1(kt+2); counted vmcnt
        LOAD_B(b, 0);
        if (kt + 2 < NT) STAGE_A(b, 1, kt + 2);
        SBAR();
        WAIT_LGKM0();
        MFMA_Q(1, 0);
        if (kt < NT - 2) { WAIT_VM6(); } else { WAIT_VM0(); }
        SBAR();
    }

    // ---- epilogue
    const float scale = *scale_p;
    const int crow0 = brow + wm * 128 + ((lane >> 4) << 2);
    const int ccol0 = bcol + wn * 64 + (lane & 15);
    float bv[4];
#pragma unroll
    for (int nf = 0; nf < 4; ++nf) bv[nf] = bias[ccol0 + nf * 16];
#pragma unroll
    for (int mf = 0; mf < 8; ++mf) {
#pragma unroll
        for (int j = 0; j < 4; ++j) {
            float* orow = out + (size_t)(crow0 + mf * 16 + j) * N_DIM;
#pragma unroll
            for (int nf = 0; nf < 4; ++nf)
                orow[ccol0 + nf * 16] = acc[mf][nf][j] * scale + bv[nf];
        }
    }
}

// ---------------- fallback (ws too small): fused dequant 128^2 GEMM ----------------
__global__ __launch_bounds__(256)
void gemm_fb_kernel(const float* __restrict__ Xf, const int* __restrict__ Wq,
                    const float* __restrict__ bias,
                    const float* __restrict__ scale_p,
                    const int* __restrict__ zp_p,
                    float* __restrict__ out) {
    const int NB = N_DIM / 128;
    int nwg = gridDim.x;
    int cpx = nwg >> 3;
    int bid = blockIdx.x;
    int swz = (bid & 7) * cpx + (bid >> 3);
    int bx = swz % NB;
    int by = swz / NB;
    const int brow = by * 128;
    const int bcol = bx * 128;

    __shared__ __align__(16) ushort sA[128 * 32];
    __shared__ __align__(16) ushort sB[128 * 32];

    const int t = threadIdx.x;
    const int lane = t & 63;
    const int wid = t >> 6;
    const int wr = wid >> 1;
    const int wc = wid & 1;

    floatx4 acc[4][4] = {};

    const int xr = t >> 1;
    const int xc = (t & 1) << 4;
    const int zp = *zp_p;

    const int arow = wr * 64 + (lane & 15);
    const int acol = (lane >> 4) << 3;
    const int brow_f = wc * 64 + (lane & 15);

    for (int k0 = 0; k0 < K_DIM; k0 += 32) {
        __syncthreads();
        const float* gx = Xf + (size_t)(brow + xr) * K_DIM + k0 + xc;
        ushort* dA = &sA[xr * 32 + xc];
#pragma unroll
        for (int i = 0; i < 4; ++i) {
            float4 v = ((const float4*)gx)[i];
            ushort4 u;
            u.x = f2bf(v.x); u.y = f2bf(v.y); u.z = f2bf(v.z); u.w = f2bf(v.w);
            *(ushort4*)(dA + i * 4) = u;
        }
        const int* gw = Wq + (size_t)(bcol + xr) * K_DIM + k0 + xc;
        ushort* dB = &sB[xr * 32 + xc];
#pragma unroll
        for (int i = 0; i < 4; ++i) {
            int4 q = ((const int4*)gw)[i];
            ushort4 u;
            u.x = f2bf((float)(q.x - zp));
            u.y = f2bf((float)(q.y - zp));
            u.z = f2bf((float)(q.z - zp));
            u.w = f2bf((float)(q.w - zp));
            *(ushort4*)(dB + i * 4) = u;
        }
        __syncthreads();

        short8 af[4], bfr[4];
#pragma unroll
        for (int m = 0; m < 4; ++m)
            af[m] = *(const short8*)&sA[(arow + m * 16) * 32 + acol];
#pragma unroll
        for (int n = 0; n < 4; ++n)
            bfr[n] = *(const short8*)&sB[(brow_f + n * 16) * 32 + acol];

#pragma unroll
        for (int m = 0; m < 4; ++m)
#pragma unroll
            for (int n = 0; n < 4; ++n)
                acc[m][n] = __builtin_amdgcn_mfma_f32_16x16x32_bf16(
                    af[m], bfr[n], acc[m][n], 0, 0, 0);
    }

    const float scale = *scale_p;
    const int colbase = bcol + wc * 64 + (lane & 15);
    const int rowbase = brow + wr * 64 + ((lane >> 4) << 2);
    float bv[4];
#pragma unroll
    for (int n = 0; n < 4; ++n) bv[n] = bias[colbase + n * 16];
#pragma unroll
    for (int m = 0; m < 4; ++m) {
        const int r0 = rowbase + m * 16;
#pragma unroll
        for (int j = 0; j < 4; ++j) {
            float* orow = out + (size_t)(r0 + j) * N_DIM;
#pragma unroll
            for (int n = 0; n < 4; ++n)
                orow[colbase + n * 16] = acc[m][n][j] * scale + bv[n];
        }
    }
}

extern "C" void kernel_launch(void* const* d_in, const int* in_sizes, int n_in,
                              void* d_out, int out_size, void* d_ws, size_t ws_size,
                              hipStream_t stream) {
    const float* x = (const float*)d_in[0];
    const int* wq = (const int*)d_in[1];
    const float* bias = (const float*)d_in[2];
    const float* scale = (const float*)d_in[3];
    const int* zp = (const int*)d_in[4];
    float* out = (float*)d_out;

    const size_t xb_bytes = (size_t)M_DIM * K_DIM * 2;  // 64 MiB
    const size_t wb_bytes = (size_t)N_DIM * K_DIM * 2;  // 128 MiB

    if (ws_size >= xb_bytes + wb_bytes) {
        ushort* xb = (ushort*)d_ws;
        ushort* wb = (ushort*)((char*)d_ws + xb_bytes);
        cvt_x_kernel<<<2048, 256, 0, stream>>>((const float4*)x, (ushort4*)xb,
                                               (M_DIM * K_DIM) / 4);
        cvt_w_kernel<<<2048, 256, 0, stream>>>((const int4*)wq, (ushort4*)wb, zp,
                                               (N_DIM * K_DIM) / 4);
        const int nblocks = (M_DIM / 256) * (N_DIM / 256);  // 2048
        gemm8_kernel<<<nblocks, 512, 0, stream>>>(xb, wb, bias, scale, out);
    } else {
        const int nblocks = (M_DIM / 128) * (N_DIM / 128);
        gemm_fb_kernel<<<nblocks, 256, 0, stream>>>(x, wq, bias, scale, zp, out);
    }
}

// Round 3
// 1041.437 us; speedup vs baseline: 1.4422x; 1.0188x over previous
//
#include <hip/hip_runtime.h>
#include <hip/hip_bf16.h>

#define M_DIM 8192
#define N_DIM 16384
#define K_DIM 4096

typedef short short8 __attribute__((ext_vector_type(8)));
typedef float floatx4 __attribute__((ext_vector_type(4)));

__device__ __forceinline__ unsigned short f2bf(float f) {
    union { float f; unsigned u; } a;
    a.f = f;
    unsigned r = a.u + 0x7FFFu + ((a.u >> 16) & 1u);
    return (unsigned short)(r >> 16);
}

#define GLDS16(g, l)                                                     \
    __builtin_amdgcn_global_load_lds(                                    \
        (const __attribute__((address_space(1))) void*)(g),              \
        (__attribute__((address_space(3))) void*)(l), 16, 0, 0)

#define SBAR() asm volatile("s_barrier" ::: "memory")
#define WAIT_LGKM0() asm volatile("s_waitcnt lgkmcnt(0)" ::: "memory")
#define WAIT_LGKM8() asm volatile("s_waitcnt lgkmcnt(8)" ::: "memory")
#define WAIT_VM6() asm volatile("s_waitcnt vmcnt(6)" ::: "memory")
#define WAIT_VM0() asm volatile("s_waitcnt vmcnt(0)" ::: "memory")
#define SCHEDB() __builtin_amdgcn_sched_barrier(0)

// ---------------- conversion kernels (memory-bound) ----------------
__global__ void cvt_x_kernel(const float4* __restrict__ x,
                             ushort4* __restrict__ out, int n4) {
    int idx = blockIdx.x * blockDim.x + threadIdx.x;
    int stride = gridDim.x * blockDim.x;
    for (int i = idx; i < n4; i += stride) {
        float4 v = x[i];
        ushort4 u;
        u.x = f2bf(v.x); u.y = f2bf(v.y); u.z = f2bf(v.z); u.w = f2bf(v.w);
        out[i] = u;
    }
}

__global__ void cvt_w_kernel(const int4* __restrict__ w,
                             ushort4* __restrict__ out,
                             const int* __restrict__ zp_p, int n4) {
    int zp = *zp_p;
    int idx = blockIdx.x * blockDim.x + threadIdx.x;
    int stride = gridDim.x * blockDim.x;
    for (int i = idx; i < n4; i += stride) {
        int4 q = w[i];
        ushort4 u;
        u.x = f2bf((float)(q.x - zp));
        u.y = f2bf((float)(q.y - zp));
        u.z = f2bf((float)(q.z - zp));
        u.w = f2bf((float)(q.w - zp));
        out[i] = u;
    }
}

// ================= 256x256 8-phase bf16 GEMM (2 K-tiles / loop iter) ==========
// Layout/swizzle/staging identical to R2 (verified). Changes: dedicated bF0/bF1
// regs (24 ds_reads per K-tile), kk-outer MFMA, branchless 2-tile-unrolled main
// loop with self-incrementing stage pointers, peeled 2-tile tail.

#define LOAD_A(BUF, MH)                                                    \
    do {                                                                   \
        const char* p_ = smem + (BUF)*65536 + (MH)*16384 + wm*8192;        \
        _Pragma("unroll") for (int mf = 0; mf < 4; ++mf) {                 \
            aF[mf][0] = *(const short8*)(p_ + mf*2048 + laneK0);           \
            aF[mf][1] = *(const short8*)(p_ + mf*2048 + laneK1);           \
        }                                                                  \
    } while (0)

#define LOAD_BR(BUF, NH, BF)                                               \
    do {                                                                   \
        const char* p_ = smem + (BUF)*65536 + 32768 + (NH)*16384 + wn*4096;\
        _Pragma("unroll") for (int nf = 0; nf < 2; ++nf) {                 \
            BF[nf][0] = *(const short8*)(p_ + nf*2048 + laneK0);           \
            BF[nf][1] = *(const short8*)(p_ + nf*2048 + laneK1);           \
        }                                                                  \
    } while (0)

// self-incrementing stage pointers: each unit advances one K-step (64 elems)
#define STAGE_A0(BUF)                                                      \
    do {                                                                   \
        GLDS16(pA00, smem + (BUF)*65536 + st16); pA00 += 64;               \
        GLDS16(pA01, smem + (BUF)*65536 + 8192 + st16); pA01 += 64;        \
    } while (0)
#define STAGE_A1(BUF)                                                      \
    do {                                                                   \
        GLDS16(pA10, smem + (BUF)*65536 + 16384 + st16); pA10 += 64;       \
        GLDS16(pA11, smem + (BUF)*65536 + 16384 + 8192 + st16); pA11 += 64;\
    } while (0)
#define STAGE_B0(BUF)                                                      \
    do {                                                                   \
        GLDS16(pB00, smem + (BUF)*65536 + 32768 + st16); pB00 += 64;       \
        GLDS16(pB01, smem + (BUF)*65536 + 32768 + 8192 + st16); pB01 += 64;\
    } while (0)
#define STAGE_B1(BUF)                                                      \
    do {                                                                   \
        GLDS16(pB10, smem + (BUF)*65536 + 49152 + st16); pB10 += 64;       \
        GLDS16(pB11, smem + (BUF)*65536 + 49152 + 8192 + st16); pB11 += 64;\
    } while (0)

// kk outer: 8 independent MFMAs per kk-group (no back-to-back same-acc deps)
#define MFMA_Q(MH, NH, BF)                                                 \
    do {                                                                   \
        __builtin_amdgcn_s_setprio(1);                                     \
        _Pragma("unroll") for (int kk = 0; kk < 2; ++kk)                   \
        _Pragma("unroll") for (int mf = 0; mf < 4; ++mf)                   \
        _Pragma("unroll") for (int nf = 0; nf < 2; ++nf)                   \
            acc[(MH)*4+mf][(NH)*2+nf] =                                    \
                __builtin_amdgcn_mfma_f32_16x16x32_bf16(                   \
                    aF[mf][kk], BF[nf][kk], acc[(MH)*4+mf][(NH)*2+nf],     \
                    0, 0, 0);                                              \
        __builtin_amdgcn_s_setprio(0);                                     \
    } while (0)

// One K-tile = 4 phases. SMODE: 2 = full staging, 1 = only next-B0, 0 = none.
#define BODY(B, NB, SMODE)                                                 \
    do {                                                                   \
        /* phase 1: quadrant (0,0) */                                      \
        LOAD_A(B, 0);                                                      \
        LOAD_BR(B, 0, bF0);                                                \
        if ((SMODE) >= 1) STAGE_B0(NB);                                    \
        WAIT_LGKM8();                                                      \
        SBAR(); WAIT_LGKM0();                                              \
        MFMA_Q(0, 0, bF0);                                                 \
        SBAR();                                                            \
        /* phase 2: quadrant (0,1) */                                      \
        LOAD_BR(B, 1, bF1);                                                \
        if ((SMODE) >= 2) STAGE_A0(B);                                     \
        SBAR(); WAIT_LGKM0();                                              \
        MFMA_Q(0, 1, bF1);                                                 \
        SBAR();                                                            \
        /* phase 3: quadrant (1,1) */                                      \
        LOAD_A(B, 1);                                                      \
        if ((SMODE) >= 2) STAGE_B1(B);                                     \
        SBAR(); WAIT_LGKM0();                                              \
        MFMA_Q(1, 1, bF1);                                                 \
        SBAR();                                                            \
        /* phase 4: quadrant (1,0) — no ds_reads, bF0 reused from regs */  \
        if ((SMODE) >= 2) STAGE_A1(B);                                     \
        SCHEDB();                                                          \
        MFMA_Q(1, 0, bF0);                                                 \
        SCHEDB();                                                          \
        if ((SMODE) == 2) { WAIT_VM6(); } else { WAIT_VM0(); }             \
        SBAR();                                                            \
    } while (0)

__global__ __launch_bounds__(512, 2)
void gemm8_kernel(const ushort* __restrict__ Aq, const ushort* __restrict__ Bq,
                  const float* __restrict__ bias,
                  const float* __restrict__ scale_p,
                  float* __restrict__ out) {
    __shared__ __align__(16) char smem[131072];

    const int t = threadIdx.x;
    const int lane = t & 63;
    const int wid = t >> 6;
    const int wm = wid >> 2;  // 0..1
    const int wn = wid & 3;   // 0..3

    // XCD-aware bijective swizzle (nwg=2048 divisible by 8)
    int bid = blockIdx.x;
    int sz = (bid & 7) * 256 + (bid >> 3);
    const int bx = sz & 63;
    const int by = sz >> 6;
    const int brow = by << 8;
    const int bcol = bx << 8;

    // swizzled ds_read lane offsets
    const int laneK0 = (lane & 15) * 128 + (((lane >> 4) * 16) ^ ((lane & 7) << 4));
    const int laneK1 = (lane & 15) * 128 + ((((lane >> 4) * 16) + 64) ^ ((lane & 7) << 4));

    // staging source offsets (inverse-swizzled), as in R2
    size_t aoffs[2], boffs[2];
#pragma unroll
    for (int g = 0; g < 2; ++g) {
        unsigned u = g * 8192 + t * 16;
        unsigned up = u ^ (((u >> 7) & 7) << 4);
        aoffs[g] = (size_t)(brow + ((up >> 13) & 1) * 128 + ((up >> 7) & 63)) * K_DIM
                   + ((up & 127) >> 1);
        boffs[g] = (size_t)(bcol + ((up >> 12) & 3) * 64 + ((up >> 7) & 31)) * K_DIM
                   + ((up & 127) >> 1);
    }
    const ushort* pA00 = Aq + aoffs[0];
    const ushort* pA01 = Aq + aoffs[1];
    const ushort* pA10 = Aq + aoffs[0] + 262144;   // mh=1: +64 rows
    const ushort* pA11 = Aq + aoffs[1] + 262144;
    const ushort* pB00 = Bq + boffs[0];
    const ushort* pB01 = Bq + boffs[1];
    const ushort* pB10 = Bq + boffs[0] + 131072;   // nh=1: +32 cols
    const ushort* pB11 = Bq + boffs[1] + 131072;
    const int st16 = t * 16;

    floatx4 acc[8][4] = {};
    short8 aF[4][2], bF0[2][2], bF1[2][2];

    const int NT = K_DIM / 64;  // 64

    // ---- prologue: tile0 complete + 3 units of tile1 (B0(1) staged at kt=0 ph1)
    STAGE_A0(0);
    STAGE_B0(0);
    STAGE_B1(0);
    STAGE_A1(0);
    STAGE_A0(1);
    STAGE_B1(1);
    STAGE_A1(1);
    WAIT_VM6();
    SBAR();

    // ---- main loop: 31 iters x 2 K-tiles, branchless
    for (int it = 0; it < (NT - 2) / 2; ++it) {
        BODY(0, 1, 2);
        BODY(1, 0, 2);
    }
    // ---- tail: kt = NT-2 (even parity), kt = NT-1
    BODY(0, 1, 1);
    BODY(1, 0, 0);

    // ---- epilogue (identical to R2)
    const float scale = *scale_p;
    const int crow0 = brow + wm * 128 + ((lane >> 4) << 2);
    const int ccol0 = bcol + wn * 64 + (lane & 15);
    float bv[4];
#pragma unroll
    for (int nf = 0; nf < 4; ++nf) bv[nf] = bias[ccol0 + nf * 16];
#pragma unroll
    for (int mf = 0; mf < 8; ++mf) {
#pragma unroll
        for (int j = 0; j < 4; ++j) {
            float* orow = out + (size_t)(crow0 + mf * 16 + j) * N_DIM;
#pragma unroll
            for (int nf = 0; nf < 4; ++nf)
                orow[ccol0 + nf * 16] = acc[mf][nf][j] * scale + bv[nf];
        }
    }
}

// ---------------- fallback (ws too small): fused dequant 128^2 GEMM ----------------
__global__ __launch_bounds__(256)
void gemm_fb_kernel(const float* __restrict__ Xf, const int* __restrict__ Wq,
                    const float* __restrict__ bias,
                    const float* __restrict__ scale_p,
                    const int* __restrict__ zp_p,
                    float* __restrict__ out) {
    const int NB = N_DIM / 128;
    int nwg = gridDim.x;
    int cpx = nwg >> 3;
    int bid = blockIdx.x;
    int swz = (bid & 7) * cpx + (bid >> 3);
    int bx = swz % NB;
    int by = swz / NB;
    const int brow = by * 128;
    const int bcol = bx * 128;

    __shared__ __align__(16) ushort sA[128 * 32];
    __shared__ __align__(16) ushort sB[128 * 32];

    const int t = threadIdx.x;
    const int lane = t & 63;
    const int wid = t >> 6;
    const int wr = wid >> 1;
    const int wc = wid & 1;

    floatx4 acc[4][4] = {};

    const int xr = t >> 1;
    const int xc = (t & 1) << 4;
    const int zp = *zp_p;

    const int arow = wr * 64 + (lane & 15);
    const int acol = (lane >> 4) << 3;
    const int brow_f = wc * 64 + (lane & 15);

    for (int k0 = 0; k0 < K_DIM; k0 += 32) {
        __syncthreads();
        const float* gx = Xf + (size_t)(brow + xr) * K_DIM + k0 + xc;
        ushort* dA = &sA[xr * 32 + xc];
#pragma unroll
        for (int i = 0; i < 4; ++i) {
            float4 v = ((const float4*)gx)[i];
            ushort4 u;
            u.x = f2bf(v.x); u.y = f2bf(v.y); u.z = f2bf(v.z); u.w = f2bf(v.w);
            *(ushort4*)(dA + i * 4) = u;
        }
        const int* gw = Wq + (size_t)(bcol + xr) * K_DIM + k0 + xc;
        ushort* dB = &sB[xr * 32 + xc];
#pragma unroll
        for (int i = 0; i < 4; ++i) {
            int4 q = ((const int4*)gw)[i];
            ushort4 u;
            u.x = f2bf((float)(q.x - zp));
            u.y = f2bf((float)(q.y - zp));
            u.z = f2bf((float)(q.z - zp));
            u.w = f2bf((float)(q.w - zp));
            *(ushort4*)(dB + i * 4) = u;
        }
        __syncthreads();

        short8 af[4], bfr[4];
#pragma unroll
        for (int m = 0; m < 4; ++m)
            af[m] = *(const short8*)&sA[(arow + m * 16) * 32 + acol];
#pragma unroll
        for (int n = 0; n < 4; ++n)
            bfr[n] = *(const short8*)&sB[(brow_f + n * 16) * 32 + acol];

#pragma unroll
        for (int m = 0; m < 4; ++m)
#pragma unroll
            for (int n = 0; n < 4; ++n)
                acc[m][n] = __builtin_amdgcn_mfma_f32_16x16x32_bf16(
                    af[m], bfr[n], acc[m][n], 0, 0, 0);
    }

    const float scale = *scale_p;
    const int colbase = bcol + wc * 64 + (lane & 15);
    const int rowbase = brow + wr * 64 + ((lane >> 4) << 2);
    float bv[4];
#pragma unroll
    for (int n = 0; n < 4; ++n) bv[n] = bias[colbase + n * 16];
#pragma unroll
    for (int m = 0; m < 4; ++m) {
        const int r0 = rowbase + m * 16;
#pragma unroll
        for (int j = 0; j < 4; ++j) {
            float* orow = out + (size_t)(r0 + j) * N_DIM;
#pragma unroll
            for (int n = 0; n < 4; ++n)
                orow[colbase + n * 16] = acc[m][n][j] * scale + bv[n];
        }
    }
}

extern "C" void kernel_launch(void* const* d_in, const int* in_sizes, int n_in,
                              void* d_out, int out_size, void* d_ws, size_t ws_size,
                              hipStream_t stream) {
    const float* x = (const float*)d_in[0];
    const int* wq = (const int*)d_in[1];
    const float* bias = (const float*)d_in[2];
    const float* scale = (const float*)d_in[3];
    const int* zp = (const int*)d_in[4];
    float* out = (float*)d_out;

    const size_t xb_bytes = (size_t)M_DIM * K_DIM * 2;  // 64 MiB
    const size_t wb_bytes = (size_t)N_DIM * K_DIM * 2;  // 128 MiB

    if (ws_size >= xb_bytes + wb_bytes) {
        ushort* xb = (ushort*)d_ws;
        ushort* wb = (ushort*)((char*)d_ws + xb_bytes);
        cvt_x_kernel<<<2048, 256, 0, stream>>>((const float4*)x, (ushort4*)xb,
                                               (M_DIM * K_DIM) / 4);
        cvt_w_kernel<<<2048, 256, 0, stream>>>((const int4*)wq, (ushort4*)wb, zp,
                                               (N_DIM * K_DIM) / 4);
        const int nblocks = (M_DIM / 256) * (N_DIM / 256);  // 2048
        gemm8_kernel<<<nblocks, 512, 0, stream>>>(xb, wb, bias, scale, out);
    } else {
        const int nblocks = (M_DIM / 128) * (N_DIM / 128);
        gemm_fb_kernel<<<nblocks, 256, 0, stream>>>(x, wq, bias, scale, zp, out);
    }
}

// Round 4
// 633.893 us; speedup vs baseline: 2.3693x; 1.6429x over previous
//
#include <hip/hip_runtime.h>
#include <hip/hip_bf16.h>
#include <stdint.h>

#define M_DIM 8192
#define N_DIM 16384
#define K_DIM 4096

typedef short short8 __attribute__((ext_vector_type(8)));
typedef float floatx4 __attribute__((ext_vector_type(4)));
typedef int i32x4 __attribute__((ext_vector_type(4)));

__device__ __forceinline__ unsigned short f2bf(float f) {
    union { float f; unsigned u; } a;
    a.f = f;
    unsigned r = a.u + 0x7FFFu + ((a.u >> 16) & 1u);
    return (unsigned short)(r >> 16);
}

#define GLDS16(g, l)                                                     \
    __builtin_amdgcn_global_load_lds(                                    \
        (const __attribute__((address_space(1))) void*)(g),              \
        (__attribute__((address_space(3))) void*)(l), 16, 0, 0)

#define SBAR() asm volatile("s_barrier" ::: "memory")
#define WAIT_LGKM0() asm volatile("s_waitcnt lgkmcnt(0)" ::: "memory")
#define WAIT_LGKM8() asm volatile("s_waitcnt lgkmcnt(8)" ::: "memory")
#define WAIT_VM6() asm volatile("s_waitcnt vmcnt(6)" ::: "memory")
#define WAIT_VM0() asm volatile("s_waitcnt vmcnt(0)" ::: "memory")
#define SCHEDB() __builtin_amdgcn_sched_barrier(0)

// ---------------- x: per-row int8 quant (scale sx[row] = absmax/127) ----------
__global__ __launch_bounds__(256)
void quant_x_kernel(const float4* __restrict__ x, int* __restrict__ xq,
                    float* __restrict__ sx) {
    const int row = blockIdx.x;
    const int t = threadIdx.x;
    const float4* px = x + (size_t)row * (K_DIM / 4);
    float4 v[4];
    float am = 0.f;
#pragma unroll
    for (int j = 0; j < 4; ++j) {
        v[j] = px[t + j * 256];
        am = fmaxf(am, fmaxf(fmaxf(fabsf(v[j].x), fabsf(v[j].y)),
                             fmaxf(fabsf(v[j].z), fabsf(v[j].w))));
    }
#pragma unroll
    for (int m = 32; m; m >>= 1) am = fmaxf(am, __shfl_xor(am, m));
    __shared__ float red[4];
    if ((t & 63) == 0) red[t >> 6] = am;
    __syncthreads();
    am = fmaxf(fmaxf(red[0], red[1]), fmaxf(red[2], red[3]));
    const float inv = am > 0.f ? 127.f / am : 0.f;
    if (t == 0) sx[row] = am * (1.f / 127.f);
    int* xo = xq + (size_t)row * (K_DIM / 4);
#pragma unroll
    for (int j = 0; j < 4; ++j) {
        int q0 = (int)rintf(v[j].x * inv);
        int q1 = (int)rintf(v[j].y * inv);
        int q2 = (int)rintf(v[j].z * inv);
        int q3 = (int)rintf(v[j].w * inv);
        xo[t + j * 256] = (q0 & 255) | ((q1 & 255) << 8) |
                          ((q2 & 255) << 16) | ((q3 & 255) << 24);
    }
}

// ---------------- w: int32 -> int8 (q - zp), exact ----------------
__global__ void cvt_w8_kernel(const int4* __restrict__ w, int4* __restrict__ out,
                              const int* __restrict__ zp_p, int n16) {
    const int zp = *zp_p;
    int idx = blockIdx.x * blockDim.x + threadIdx.x;
    int stride = gridDim.x * blockDim.x;
    for (int i = idx; i < n16; i += stride) {
        int4 r;
        int* rp = (int*)&r;
#pragma unroll
        for (int j = 0; j < 4; ++j) {
            int4 q = w[i * 4 + j];
            rp[j] = ((q.x - zp) & 255) | (((q.y - zp) & 255) << 8) |
                    (((q.z - zp) & 255) << 16) | (((q.w - zp) & 255) << 24);
        }
        out[i] = r;
    }
}

// ================= 256x256 8-phase int8 GEMM (BK=128, 2 K-tiles/iter) =========
// LDS byte layout identical to the verified bf16 R3 kernel: per buffer
// A = 256 slices x 128B, B = 256 slices x 128B, XOR-swizzle byte^=((row&7)<<4),
// linear global_load_lds dest + inverse-swizzled global source.
// Fragments: i8 16x16x64 MFMA, per-lane 16 contiguous k-bytes at
// (lane>>4)*16 within each 64B k-half (kk=0: bytes 0-63, kk=1: 64-127).

#define LOAD_A(BUF, MH)                                                    \
    do {                                                                   \
        const char* p_ = smem + (BUF)*65536 + (MH)*16384 + wm*8192;        \
        _Pragma("unroll") for (int mf = 0; mf < 4; ++mf) {                 \
            aF[mf][0] = *(const i32x4*)(p_ + mf*2048 + laneK0);            \
            aF[mf][1] = *(const i32x4*)(p_ + mf*2048 + laneK1);            \
        }                                                                  \
    } while (0)

#define LOAD_BR(BUF, NH, BF)                                               \
    do {                                                                   \
        const char* p_ = smem + (BUF)*65536 + 32768 + (NH)*16384 + wn*4096;\
        _Pragma("unroll") for (int nf = 0; nf < 2; ++nf) {                 \
            BF[nf][0] = *(const i32x4*)(p_ + nf*2048 + laneK0);            \
            BF[nf][1] = *(const i32x4*)(p_ + nf*2048 + laneK1);            \
        }                                                                  \
    } while (0)

// self-incrementing stage pointers: each unit advances one K-tile (128 bytes)
#define STAGE_A0(BUF)                                                      \
    do {                                                                   \
        GLDS16(pA00, smem + (BUF)*65536 + st16); pA00 += 128;              \
        GLDS16(pA01, smem + (BUF)*65536 + 8192 + st16); pA01 += 128;       \
    } while (0)
#define STAGE_A1(BUF)                                                      \
    do {                                                                   \
        GLDS16(pA10, smem + (BUF)*65536 + 16384 + st16); pA10 += 128;      \
        GLDS16(pA11, smem + (BUF)*65536 + 16384 + 8192 + st16); pA11 += 128;\
    } while (0)
#define STAGE_B0(BUF)                                                      \
    do {                                                                   \
        GLDS16(pB00, smem + (BUF)*65536 + 32768 + st16); pB00 += 128;      \
        GLDS16(pB01, smem + (BUF)*65536 + 32768 + 8192 + st16); pB01 += 128;\
    } while (0)
#define STAGE_B1(BUF)                                                      \
    do {                                                                   \
        GLDS16(pB10, smem + (BUF)*65536 + 49152 + st16); pB10 += 128;      \
        GLDS16(pB11, smem + (BUF)*65536 + 49152 + 8192 + st16); pB11 += 128;\
    } while (0)

#define MFMA_Q(MH, NH, BF)                                                 \
    do {                                                                   \
        __builtin_amdgcn_s_setprio(1);                                     \
        _Pragma("unroll") for (int kk = 0; kk < 2; ++kk)                   \
        _Pragma("unroll") for (int mf = 0; mf < 4; ++mf)                   \
        _Pragma("unroll") for (int nf = 0; nf < 2; ++nf)                   \
            acc[(MH)*4+mf][(NH)*2+nf] =                                    \
                __builtin_amdgcn_mfma_i32_16x16x64_i8(                     \
                    aF[mf][kk], BF[nf][kk], acc[(MH)*4+mf][(NH)*2+nf],     \
                    0, 0, 0);                                              \
        __builtin_amdgcn_s_setprio(0);                                     \
    } while (0)

#define BODY(B, NB, SMODE)                                                 \
    do {                                                                   \
        /* phase 1: quadrant (0,0) */                                      \
        LOAD_A(B, 0);                                                      \
        LOAD_BR(B, 0, bF0);                                                \
        if ((SMODE) >= 1) STAGE_B0(NB);                                    \
        WAIT_LGKM8();                                                      \
        SBAR(); WAIT_LGKM0();                                              \
        MFMA_Q(0, 0, bF0);                                                 \
        SBAR();                                                            \
        /* phase 2: quadrant (0,1) */                                      \
        LOAD_BR(B, 1, bF1);                                                \
        if ((SMODE) >= 2) STAGE_A0(B);                                     \
        SBAR(); WAIT_LGKM0();                                              \
        MFMA_Q(0, 1, bF1);                                                 \
        SBAR();                                                            \
        /* phase 3: quadrant (1,1) */                                      \
        LOAD_A(B, 1);                                                      \
        if ((SMODE) >= 2) STAGE_B1(B);                                     \
        SBAR(); WAIT_LGKM0();                                              \
        MFMA_Q(1, 1, bF1);                                                 \
        SBAR();                                                            \
        /* phase 4: quadrant (1,0) — no ds_reads, bF0 reused from regs */  \
        if ((SMODE) >= 2) STAGE_A1(B);                                     \
        SCHEDB();                                                          \
        MFMA_Q(1, 0, bF0);                                                 \
        SCHEDB();                                                          \
        if ((SMODE) == 2) { WAIT_VM6(); } else { WAIT_VM0(); }             \
        SBAR();                                                            \
    } while (0)

__global__ __launch_bounds__(512, 2)
void gemm8i_kernel(const int8_t* __restrict__ Aq, const int8_t* __restrict__ Bq,
                   const float* __restrict__ bias,
                   const float* __restrict__ scale_p,
                   const float* __restrict__ sx,
                   float* __restrict__ out) {
    __shared__ __align__(16) char smem[131072];

    const int t = threadIdx.x;
    const int lane = t & 63;
    const int wid = t >> 6;
    const int wm = wid >> 2;  // 0..1
    const int wn = wid & 3;   // 0..3

    // XCD-aware bijective swizzle (nwg=2048 divisible by 8)
    int bid = blockIdx.x;
    int sz = (bid & 7) * 256 + (bid >> 3);
    const int bx = sz & 63;
    const int by = sz >> 6;
    const int brow = by << 8;
    const int bcol = bx << 8;

    // swizzled ds_read lane offsets (128B rows, 16B slots)
    const int laneK0 = (lane & 15) * 128 + (((lane >> 4) * 16) ^ ((lane & 7) << 4));
    const int laneK1 = (lane & 15) * 128 + ((((lane >> 4) * 16) + 64) ^ ((lane & 7) << 4));

    // staging source offsets (inverse-swizzled); 1 byte per element
    size_t aoffs[2], boffs[2];
#pragma unroll
    for (int g = 0; g < 2; ++g) {
        unsigned u = g * 8192 + t * 16;
        unsigned up = u ^ (((u >> 7) & 7) << 4);
        aoffs[g] = (size_t)(brow + ((up >> 13) & 1) * 128 + ((up >> 7) & 63)) * K_DIM
                   + (up & 127);
        boffs[g] = (size_t)(bcol + ((up >> 12) & 3) * 64 + ((up >> 7) & 31)) * K_DIM
                   + (up & 127);
    }
    const int8_t* pA00 = Aq + aoffs[0];
    const int8_t* pA01 = Aq + aoffs[1];
    const int8_t* pA10 = Aq + aoffs[0] + 262144;   // +64 rows
    const int8_t* pA11 = Aq + aoffs[1] + 262144;
    const int8_t* pB00 = Bq + boffs[0];
    const int8_t* pB01 = Bq + boffs[1];
    const int8_t* pB10 = Bq + boffs[0] + 131072;   // +32 cols
    const int8_t* pB11 = Bq + boffs[1] + 131072;
    const int st16 = t * 16;

    i32x4 acc[8][4] = {};
    i32x4 aF[4][2], bF0[2][2], bF1[2][2];

    const int NT = K_DIM / 128;  // 32

    // ---- prologue: tile0 complete + 3 units of tile1 (B0(1) staged at kt=0 ph1)
    STAGE_A0(0);
    STAGE_B0(0);
    STAGE_B1(0);
    STAGE_A1(0);
    STAGE_A0(1);
    STAGE_B1(1);
    STAGE_A1(1);
    WAIT_VM6();
    SBAR();

    // ---- main loop: 15 iters x 2 K-tiles, branchless
    for (int it = 0; it < (NT - 2) / 2; ++it) {
        BODY(0, 1, 2);
        BODY(1, 0, 2);
    }
    // ---- tail
    BODY(0, 1, 1);
    BODY(1, 0, 0);

    // ---- epilogue: out = acc * (scale*sx[row]) + bias[col]
    const float scale = *scale_p;
    const int crow0 = brow + wm * 128 + ((lane >> 4) << 2);
    const int ccol0 = bcol + wn * 64 + (lane & 15);
    float bv[4];
#pragma unroll
    for (int nf = 0; nf < 4; ++nf) bv[nf] = bias[ccol0 + nf * 16];
#pragma unroll
    for (int mf = 0; mf < 8; ++mf) {
#pragma unroll
        for (int j = 0; j < 4; ++j) {
            const int r = crow0 + mf * 16 + j;
            const float s2 = scale * sx[r];
            float* orow = out + (size_t)r * N_DIM;
#pragma unroll
            for (int nf = 0; nf < 4; ++nf)
                orow[ccol0 + nf * 16] = (float)acc[mf][nf][j] * s2 + bv[nf];
        }
    }
}

// ---------------- fallback (ws too small): fused dequant 128^2 bf16 GEMM ------
__global__ __launch_bounds__(256)
void gemm_fb_kernel(const float* __restrict__ Xf, const int* __restrict__ Wq,
                    const float* __restrict__ bias,
                    const float* __restrict__ scale_p,
                    const int* __restrict__ zp_p,
                    float* __restrict__ out) {
    const int NB = N_DIM / 128;
    int nwg = gridDim.x;
    int cpx = nwg >> 3;
    int bid = blockIdx.x;
    int swz = (bid & 7) * cpx + (bid >> 3);
    int bx = swz % NB;
    int by = swz / NB;
    const int brow = by * 128;
    const int bcol = bx * 128;

    __shared__ __align__(16) ushort sA[128 * 32];
    __shared__ __align__(16) ushort sB[128 * 32];

    const int t = threadIdx.x;
    const int lane = t & 63;
    const int wid = t >> 6;
    const int wr = wid >> 1;
    const int wc = wid & 1;

    floatx4 acc[4][4] = {};

    const int xr = t >> 1;
    const int xc = (t & 1) << 4;
    const int zp = *zp_p;

    const int arow = wr * 64 + (lane & 15);
    const int acol = (lane >> 4) << 3;
    const int brow_f = wc * 64 + (lane & 15);

    for (int k0 = 0; k0 < K_DIM; k0 += 32) {
        __syncthreads();
        const float* gx = Xf + (size_t)(brow + xr) * K_DIM + k0 + xc;
        ushort* dA = &sA[xr * 32 + xc];
#pragma unroll
        for (int i = 0; i < 4; ++i) {
            float4 v = ((const float4*)gx)[i];
            ushort4 u;
            u.x = f2bf(v.x); u.y = f2bf(v.y); u.z = f2bf(v.z); u.w = f2bf(v.w);
            *(ushort4*)(dA + i * 4) = u;
        }
        const int* gw = Wq + (size_t)(bcol + xr) * K_DIM + k0 + xc;
        ushort* dB = &sB[xr * 32 + xc];
#pragma unroll
        for (int i = 0; i < 4; ++i) {
            int4 q = ((const int4*)gw)[i];
            ushort4 u;
            u.x = f2bf((float)(q.x - zp));
            u.y = f2bf((float)(q.y - zp));
            u.z = f2bf((float)(q.z - zp));
            u.w = f2bf((float)(q.w - zp));
            *(ushort4*)(dB + i * 4) = u;
        }
        __syncthreads();

        short8 af[4], bfr[4];
#pragma unroll
        for (int m = 0; m < 4; ++m)
            af[m] = *(const short8*)&sA[(arow + m * 16) * 32 + acol];
#pragma unroll
        for (int n = 0; n < 4; ++n)
            bfr[n] = *(const short8*)&sB[(brow_f + n * 16) * 32 + acol];

#pragma unroll
        for (int m = 0; m < 4; ++m)
#pragma unroll
            for (int n = 0; n < 4; ++n)
                acc[m][n] = __builtin_amdgcn_mfma_f32_16x16x32_bf16(
                    af[m], bfr[n], acc[m][n], 0, 0, 0);
    }

    const float scale = *scale_p;
    const int colbase = bcol + wc * 64 + (lane & 15);
    const int rowbase = brow + wr * 64 + ((lane >> 4) << 2);
    float bv[4];
#pragma unroll
    for (int n = 0; n < 4; ++n) bv[n] = bias[colbase + n * 16];
#pragma unroll
    for (int m = 0; m < 4; ++m) {
        const int r0 = rowbase + m * 16;
#pragma unroll
        for (int j = 0; j < 4; ++j) {
            float* orow = out + (size_t)(r0 + j) * N_DIM;
#pragma unroll
            for (int n = 0; n < 4; ++n)
                orow[colbase + n * 16] = acc[m][n][j] * scale + bv[n];
        }
    }
}

extern "C" void kernel_launch(void* const* d_in, const int* in_sizes, int n_in,
                              void* d_out, int out_size, void* d_ws, size_t ws_size,
                              hipStream_t stream) {
    const float* x = (const float*)d_in[0];
    const int* wq = (const int*)d_in[1];
    const float* bias = (const float*)d_in[2];
    const float* scale = (const float*)d_in[3];
    const int* zp = (const int*)d_in[4];
    float* out = (float*)d_out;

    const size_t xq_bytes = (size_t)M_DIM * K_DIM;       // 32 MiB
    const size_t wb_bytes = (size_t)N_DIM * K_DIM;       // 64 MiB
    const size_t sx_bytes = (size_t)M_DIM * 4;           // 32 KiB

    if (ws_size >= xq_bytes + wb_bytes + sx_bytes) {
        int8_t* xq = (int8_t*)d_ws;
        int8_t* wb = (int8_t*)d_ws + xq_bytes;
        float* sx = (float*)((char*)d_ws + xq_bytes + wb_bytes);
        quant_x_kernel<<<M_DIM, 256, 0, stream>>>((const float4*)x, (int*)xq, sx);
        cvt_w8_kernel<<<2048, 256, 0, stream>>>((const int4*)wq, (int4*)wb, zp,
                                                (N_DIM * K_DIM) / 16);
        const int nblocks = (M_DIM / 256) * (N_DIM / 256);  // 2048
        gemm8i_kernel<<<nblocks, 512, 0, stream>>>(xq, wb, bias, scale, sx, out);
    } else {
        const int nblocks = (M_DIM / 128) * (N_DIM / 128);
        gemm_fb_kernel<<<nblocks, 256, 0, stream>>>(x, wq, bias, scale, zp, out);
    }
}